// Round 1
// baseline (27.300 us; speedup 1.0000x reference)
//
#include <hip/hip_runtime.h>

// Problem constants (from reference):
//   B=8, V=6890, C=16, F=13776, FTOT=B*F=110208, H=W=512, K=1
//   npix = B*H*W*K = 2,097,152
// Output: int32 [B,H,W,K] = channel 0 of barycentric-interpolated
// per-vertex class features, truncated toward zero; 0 for background.

#define VC_C 16

// Kernel 1: pre-gather channel-0 vertex attribute for each face's 3 verts
// into a compact float4 table (L2-resident, 1.76 MB).
__global__ void gather_face_attr_kernel(const float* __restrict__ vc,
                                        const int* __restrict__ faces,
                                        float4* __restrict__ fa, int ftot) {
    int f = blockIdx.x * blockDim.x + threadIdx.x;
    if (f >= ftot) return;
    int v0 = faces[3 * f + 0];
    int v1 = faces[3 * f + 1];
    int v2 = faces[3 * f + 2];
    fa[f] = make_float4(vc[(long long)v0 * VC_C],
                        vc[(long long)v1 * VC_C],
                        vc[(long long)v2 * VC_C], 0.0f);
}

// Kernel 2: 4 pixels per thread. Coalesced int4 / float4 loads, one float4
// gather per valid pixel, int4 store.
__global__ void seg_shader_kernel(const float4* __restrict__ fa,
                                  const int* __restrict__ p2f,
                                  const float* __restrict__ bary,
                                  int* __restrict__ out, int npix4) {
    int i = blockIdx.x * blockDim.x + threadIdx.x;
    if (i >= npix4) return;
    int base = i * 4;

    const int4 pf = *reinterpret_cast<const int4*>(p2f + base);
    // bary is [npix,3] floats; byte offset 48*i is 16-aligned.
    const float4 b0 = *reinterpret_cast<const float4*>(bary + (long long)base * 3);
    const float4 b1 = *reinterpret_cast<const float4*>(bary + (long long)base * 3 + 4);
    const float4 b2 = *reinterpret_cast<const float4*>(bary + (long long)base * 3 + 8);

    float w[12] = {b0.x, b0.y, b0.z, b0.w,
                   b1.x, b1.y, b1.z, b1.w,
                   b2.x, b2.y, b2.z, b2.w};
    int pfv[4] = {pf.x, pf.y, pf.z, pf.w};
    int res[4];

#pragma unroll
    for (int j = 0; j < 4; ++j) {
        int r = 0;
        int f = pfv[j];
        if (f >= 0) {
            float4 a = fa[f];
            float s = w[3 * j + 0] * a.x + w[3 * j + 1] * a.y + w[3 * j + 2] * a.z;
            r = (int)s;  // trunc toward zero == astype(int32)
        }
        res[j] = r;
    }

    int4 o = make_int4(res[0], res[1], res[2], res[3]);
    *reinterpret_cast<int4*>(out + base) = o;
}

// Fallback (no workspace): direct gathers, 1 pixel per thread.
__global__ void seg_shader_direct_kernel(const float* __restrict__ vc,
                                         const int* __restrict__ faces,
                                         const int* __restrict__ p2f,
                                         const float* __restrict__ bary,
                                         int* __restrict__ out, int npix) {
    int i = blockIdx.x * blockDim.x + threadIdx.x;
    if (i >= npix) return;
    int f = p2f[i];
    int r = 0;
    if (f >= 0) {
        int v0 = faces[3 * f + 0];
        int v1 = faces[3 * f + 1];
        int v2 = faces[3 * f + 2];
        float w0 = bary[3 * (long long)i + 0];
        float w1 = bary[3 * (long long)i + 1];
        float w2 = bary[3 * (long long)i + 2];
        float s = w0 * vc[(long long)v0 * VC_C] +
                  w1 * vc[(long long)v1 * VC_C] +
                  w2 * vc[(long long)v2 * VC_C];
        r = (int)s;
    }
    out[i] = r;
}

extern "C" void kernel_launch(void* const* d_in, const int* in_sizes, int n_in,
                              void* d_out, int out_size, void* d_ws, size_t ws_size,
                              hipStream_t stream) {
    const float* verts_class = (const float*)d_in[0];   // [B*V*C] f32
    const int*   faces       = (const int*)d_in[1];     // [FTOT*3] i32
    const int*   pix_to_face = (const int*)d_in[2];     // [npix] i32
    const float* bary        = (const float*)d_in[3];   // [npix*3] f32
    int*         out         = (int*)d_out;             // [npix] i32

    const int ftot = in_sizes[1] / 3;
    const int npix = out_size;
    const size_t fa_bytes = (size_t)ftot * sizeof(float4);

    if (d_ws != nullptr && ws_size >= fa_bytes && (npix % 4) == 0) {
        float4* fa = (float4*)d_ws;
        {
            int threads = 256;
            int blocks = (ftot + threads - 1) / threads;
            gather_face_attr_kernel<<<blocks, threads, 0, stream>>>(
                verts_class, faces, fa, ftot);
        }
        {
            int npix4 = npix / 4;
            int threads = 256;
            int blocks = (npix4 + threads - 1) / threads;
            seg_shader_kernel<<<blocks, threads, 0, stream>>>(
                fa, pix_to_face, bary, out, npix4);
        }
    } else {
        int threads = 256;
        int blocks = (npix + threads - 1) / threads;
        seg_shader_direct_kernel<<<blocks, threads, 0, stream>>>(
            verts_class, faces, pix_to_face, bary, out, npix);
    }
}